// Round 1
// baseline (326.207 us; speedup 1.0000x reference)
//
#include <hip/hip_runtime.h>
#include <math.h>

#define BATCH 16
#define H 1024
#define W 1024
#define WSZ 11
#define OH (H - WSZ + 1)   // 1014
#define OW (W - WSZ + 1)   // 1014
#define NPIX ((size_t)BATCH * H * W)

#define TPB 256
#define CPT 4              // columns per thread (256*4 = 1024 = full width)
#define RSTRIP 32          // output rows per block

#define INV121 (1.0f / 121.0f)

__device__ __forceinline__ unsigned int f2key(float f) {
  unsigned int u = __float_as_uint(f);
  return (u & 0x80000000u) ? ~u : (u | 0x80000000u);
}
__device__ __forceinline__ float key2f(unsigned int k) {
  unsigned int u = (k & 0x80000000u) ? (k ^ 0x80000000u) : ~k;
  return __uint_as_float(u);
}

// ws layout: bytes [0..16) = 4 uint keys (min1,max1,min2,max2); [16..24) = double sum
__global__ void init_ws(unsigned int* keys, double* dsum) {
  keys[0] = 0xFFFFFFFFu; keys[1] = 0u;
  keys[2] = 0xFFFFFFFFu; keys[3] = 0u;
  *dsum = 0.0;
}

__global__ void __launch_bounds__(256) minmax_kernel(
    const float* __restrict__ a, const float* __restrict__ b,
    unsigned int* __restrict__ keys) {
  const size_t n4 = NPIX / 4;
  float mn1 = 1e30f, mx1 = -1e30f, mn2 = 1e30f, mx2 = -1e30f;
  const float4* a4 = (const float4*)a;
  const float4* b4 = (const float4*)b;
  for (size_t i = (size_t)blockIdx.x * blockDim.x + threadIdx.x; i < n4;
       i += (size_t)gridDim.x * blockDim.x) {
    float4 x = a4[i];
    mn1 = fminf(mn1, fminf(fminf(x.x, x.y), fminf(x.z, x.w)));
    mx1 = fmaxf(mx1, fmaxf(fmaxf(x.x, x.y), fmaxf(x.z, x.w)));
    float4 y = b4[i];
    mn2 = fminf(mn2, fminf(fminf(y.x, y.y), fminf(y.z, y.w)));
    mx2 = fmaxf(mx2, fmaxf(fmaxf(y.x, y.y), fmaxf(y.z, y.w)));
  }
#pragma unroll
  for (int off = 32; off > 0; off >>= 1) {
    mn1 = fminf(mn1, __shfl_down(mn1, off));
    mx1 = fmaxf(mx1, __shfl_down(mx1, off));
    mn2 = fminf(mn2, __shfl_down(mn2, off));
    mx2 = fmaxf(mx2, __shfl_down(mx2, off));
  }
  __shared__ float s[4][4];  // [quantity][wave]
  const int wave = threadIdx.x >> 6, lane = threadIdx.x & 63;
  if (lane == 0) { s[0][wave] = mn1; s[1][wave] = mx1; s[2][wave] = mn2; s[3][wave] = mx2; }
  __syncthreads();
  if (threadIdx.x == 0) {
    mn1 = fminf(fminf(s[0][0], s[0][1]), fminf(s[0][2], s[0][3]));
    mx1 = fmaxf(fmaxf(s[1][0], s[1][1]), fmaxf(s[1][2], s[1][3]));
    mn2 = fminf(fminf(s[2][0], s[2][1]), fminf(s[2][2], s[2][3]));
    mx2 = fmaxf(fmaxf(s[3][0], s[3][1]), fmaxf(s[3][2], s[3][3]));
    atomicMin(&keys[0], f2key(mn1));
    atomicMax(&keys[1], f2key(mx1));
    atomicMin(&keys[2], f2key(mn2));
    atomicMax(&keys[3], f2key(mx2));
  }
}

__global__ void __launch_bounds__(TPB) tmqi_kernel(
    const float* __restrict__ img1, const float* __restrict__ img2,
    const unsigned int* __restrict__ keys, double* __restrict__ dsum,
    float uhdr, float inv_s) {
  __shared__ float cs[5][W + 16];  // +16 pad so last thread's 16-wide read stays in-bounds
  __shared__ double wred[TPB / 64];

  const int tid = threadIdx.x;
  const int r0 = blockIdx.x * RSTRIP;
  const int b = blockIdx.y;
  const int rs = min(RSTRIP, OH - r0);
  const int c = tid * CPT;  // first input column owned by this thread

  const float a1 = 255.0f / (key2f(keys[1]) - key2f(keys[0]) + 1e-6f);
  const float a2 = 255.0f / (key2f(keys[3]) - key2f(keys[2]) + 1e-6f);

  const float* p1 = img1 + ((size_t)b << 20) + c;
  const float* p2 = img2 + ((size_t)b << 20) + c;

  float su[4], sv[4], suu[4], svv[4], suv[4];
#pragma unroll
  for (int k = 0; k < 4; ++k) { su[k] = sv[k] = suu[k] = svv[k] = suv[k] = 0.0f; }

  // prologue: vertical sums over first 11 rows
#pragma unroll 1
  for (int r = r0; r < r0 + WSZ; ++r) {
    float4 u4 = *(const float4*)(p1 + ((size_t)r << 10));
    float4 v4 = *(const float4*)(p2 + ((size_t)r << 10));
    float uu[4] = {u4.x, u4.y, u4.z, u4.w};
    float vv[4] = {v4.x, v4.y, v4.z, v4.w};
#pragma unroll
    for (int k = 0; k < 4; ++k) {
      su[k] += uu[k]; sv[k] += vv[k];
      suu[k] = fmaf(uu[k], uu[k], suu[k]);
      svv[k] = fmaf(vv[k], vv[k], svv[k]);
      suv[k] = fmaf(uu[k], vv[k], suv[k]);
    }
  }

  double acc = 0.0;

#pragma unroll 1
  for (int i = 0; i < rs; ++i) {
    // publish vertical sums
    ((float4*)(cs[0]))[tid] = make_float4(su[0], su[1], su[2], su[3]);
    ((float4*)(cs[1]))[tid] = make_float4(sv[0], sv[1], sv[2], sv[3]);
    ((float4*)(cs[2]))[tid] = make_float4(suu[0], suu[1], suu[2], suu[3]);
    ((float4*)(cs[3]))[tid] = make_float4(svv[0], svv[1], svv[2], svv[3]);
    ((float4*)(cs[4]))[tid] = make_float4(suv[0], suv[1], suv[2], suv[3]);
    __syncthreads();

    if (c < OW) {
      float S[5][4];
#pragma unroll
      for (int q = 0; q < 5; ++q) {
        const float* row = cs[q];
        float4 w0 = *(const float4*)(row + c);
        float4 w1 = *(const float4*)(row + c + 4);
        float4 w2 = *(const float4*)(row + c + 8);
        float4 w3 = *(const float4*)(row + c + 12);
        float s0 = w0.x + w0.y + w0.z + w0.w + w1.x + w1.y + w1.z + w1.w +
                   w2.x + w2.y + w2.z;
        S[q][0] = s0;
        float s1 = s0 - w0.x + w2.w; S[q][1] = s1;
        float s2 = s1 - w0.y + w3.x; S[q][2] = s2;
        float s3 = s2 - w0.z + w3.y; S[q][3] = s3;
      }
#pragma unroll
      for (int k = 0; k < 4; ++k) {
        if (c + k < OW) {
          float mu_u = S[0][k] * INV121;
          float mu_v = S[1][k] * INV121;
          float varu = fmaf(-mu_u, mu_u, S[2][k] * INV121);
          float varv = fmaf(-mu_v, mu_v, S[3][k] * INV121);
          float cov  = fmaf(-mu_u, mu_v, S[4][k] * INV121);
          float s1sq = a1 * a1 * varu;
          float s2sq = a2 * a2 * varv;
          float s12  = a1 * a2 * cov;
          float sg1 = sqrtf(fmaxf(s1sq, 0.0f) + 1e-6f);
          float sg2 = sqrtf(fmaxf(s2sq, 0.0f) + 1e-6f);
          float pp1 = 0.5f * (1.0f + erff((sg1 - uhdr) * inv_s));
          float pp2 = 0.5f * (1.0f + erff((sg2 - uhdr) * inv_s));
          float smap = ((2.0f * pp1 * pp2 + 0.01f) / (pp1 * pp1 + pp2 * pp2 + 0.01f)) *
                       ((s12 + 10.0f) / (sg1 * sg2 + 10.0f));
          acc += (double)smap;
        }
      }
    }
    __syncthreads();

    // slide window down one row
    if (i + 1 < rs) {
      const int rn = r0 + i + WSZ;
      const int ro = r0 + i;
      float4 un4 = *(const float4*)(p1 + ((size_t)rn << 10));
      float4 vn4 = *(const float4*)(p2 + ((size_t)rn << 10));
      float4 uo4 = *(const float4*)(p1 + ((size_t)ro << 10));
      float4 vo4 = *(const float4*)(p2 + ((size_t)ro << 10));
      float un[4] = {un4.x, un4.y, un4.z, un4.w};
      float vn[4] = {vn4.x, vn4.y, vn4.z, vn4.w};
      float uo[4] = {uo4.x, uo4.y, uo4.z, uo4.w};
      float vo[4] = {vo4.x, vo4.y, vo4.z, vo4.w};
#pragma unroll
      for (int k = 0; k < 4; ++k) {
        su[k] += un[k] - uo[k];
        sv[k] += vn[k] - vo[k];
        suu[k] += fmaf(un[k], un[k], -uo[k] * uo[k]);
        svv[k] += fmaf(vn[k], vn[k], -vo[k] * vo[k]);
        suv[k] += fmaf(un[k], vn[k], -uo[k] * vo[k]);
      }
    }
  }

  // block reduce (double)
#pragma unroll
  for (int off = 32; off > 0; off >>= 1) acc += __shfl_down(acc, off);
  if ((tid & 63) == 0) wred[tid >> 6] = acc;
  __syncthreads();
  if (tid == 0) atomicAdd(dsum, wred[0] + wred[1] + wred[2] + wred[3]);
}

__global__ void finalize_kernel(const double* __restrict__ dsum, float* __restrict__ out) {
  out[0] = (float)(*dsum / (double)((size_t)BATCH * OH * OW));
}

extern "C" void kernel_launch(void* const* d_in, const int* in_sizes, int n_in,
                              void* d_out, int out_size, void* d_ws, size_t ws_size,
                              hipStream_t stream) {
  const float* img1 = (const float*)d_in[0];
  const float* img2 = (const float*)d_in[1];
  float* out = (float*)d_out;

  unsigned int* keys = (unsigned int*)d_ws;
  double* dsum = (double*)((char*)d_ws + 16);

  // TMQI constants (host-side double math, matches reference numpy)
  const double csf = 100.0 * 2.6 * (0.0192 + 0.114 * 16.0) * exp(-pow(0.114 * 16.0, 1.1));
  const double u_hdr = 128.0 / (1.4 * csf);
  const double sig_hdr = u_hdr / 3.0;
  const float uhdr = (float)u_hdr;
  const float inv_s = (float)(1.0 / (sig_hdr * sqrt(2.0)));

  hipLaunchKernelGGL(init_ws, dim3(1), dim3(1), 0, stream, keys, dsum);
  hipLaunchKernelGGL(minmax_kernel, dim3(2048), dim3(256), 0, stream, img1, img2, keys);
  dim3 grid((OH + RSTRIP - 1) / RSTRIP, BATCH);
  hipLaunchKernelGGL(tmqi_kernel, grid, dim3(TPB), 0, stream,
                     img1, img2, keys, dsum, uhdr, inv_s);
  hipLaunchKernelGGL(finalize_kernel, dim3(1), dim3(1), 0, stream, dsum, out);
}

// Round 2
// 264.026 us; speedup vs baseline: 1.2355x; 1.2355x over previous
//
#include <hip/hip_runtime.h>
#include <math.h>

#define BATCH 16
#define H 1024
#define W 1024
#define WSZ 11
#define OH (H - WSZ + 1)   // 1014
#define OW (W - WSZ + 1)   // 1014
#define NPIX ((size_t)BATCH * H * W)

// minmax config: exact cover, no grid-stride loop
#define MM_BLOCKS 1024
#define MM_TPB 256
#define MM_PT 16           // float4 per thread per image; 1024*256*16 = NPIX/4 exactly

// tmqi config
#define TPB 256
#define CPT 4              // 256*4 = 1024 = full width
#define RSTRIP 16          // output rows per block -> 64 strips
#define NSTRIP ((OH + RSTRIP - 1) / RSTRIP)
#define TGRID (NSTRIP * BATCH)  // 1024 blocks

#define INV121 (1.0f / 121.0f)

__device__ __forceinline__ unsigned int f2key(float f) {
  unsigned int u = __float_as_uint(f);
  return (u & 0x80000000u) ? ~u : (u | 0x80000000u);
}
__device__ __forceinline__ float key2f(unsigned int k) {
  unsigned int u = (k & 0x80000000u) ? (k ^ 0x80000000u) : ~k;
  return __uint_as_float(u);
}

// ws layout: [0..16) 4 uint keys (min1,max1,min2,max2); [16..24) double sum; [24..28) uint counter
__global__ void init_ws(unsigned int* keys, double* dsum, unsigned int* cnt) {
  keys[0] = 0xFFFFFFFFu; keys[1] = 0u;
  keys[2] = 0xFFFFFFFFu; keys[3] = 0u;
  *dsum = 0.0;
  *cnt = 0u;
}

__global__ void __launch_bounds__(MM_TPB) minmax_kernel(
    const float4* __restrict__ a4, const float4* __restrict__ b4,
    unsigned int* __restrict__ keys) {
  const int tid = threadIdx.x;
  const size_t base = (size_t)blockIdx.x * (MM_TPB * MM_PT) + tid;
  float mn1 = 1e30f, mx1 = -1e30f, mn2 = 1e30f, mx2 = -1e30f;
  float4 r[8];
#pragma unroll
  for (int h = 0; h < 2; ++h) {
#pragma unroll
    for (int k = 0; k < 8; ++k) r[k] = a4[base + (size_t)(h * 8 + k) * MM_TPB];
#pragma unroll
    for (int k = 0; k < 8; ++k) {
      mn1 = fminf(mn1, fminf(fminf(r[k].x, r[k].y), fminf(r[k].z, r[k].w)));
      mx1 = fmaxf(mx1, fmaxf(fmaxf(r[k].x, r[k].y), fmaxf(r[k].z, r[k].w)));
    }
  }
#pragma unroll
  for (int h = 0; h < 2; ++h) {
#pragma unroll
    for (int k = 0; k < 8; ++k) r[k] = b4[base + (size_t)(h * 8 + k) * MM_TPB];
#pragma unroll
    for (int k = 0; k < 8; ++k) {
      mn2 = fminf(mn2, fminf(fminf(r[k].x, r[k].y), fminf(r[k].z, r[k].w)));
      mx2 = fmaxf(mx2, fmaxf(fmaxf(r[k].x, r[k].y), fmaxf(r[k].z, r[k].w)));
    }
  }
#pragma unroll
  for (int off = 32; off > 0; off >>= 1) {
    mn1 = fminf(mn1, __shfl_down(mn1, off));
    mx1 = fmaxf(mx1, __shfl_down(mx1, off));
    mn2 = fminf(mn2, __shfl_down(mn2, off));
    mx2 = fmaxf(mx2, __shfl_down(mx2, off));
  }
  __shared__ float s[4][4];
  const int wave = tid >> 6, lane = tid & 63;
  if (lane == 0) { s[0][wave] = mn1; s[1][wave] = mx1; s[2][wave] = mn2; s[3][wave] = mx2; }
  __syncthreads();
  if (tid == 0) {
    mn1 = fminf(fminf(s[0][0], s[0][1]), fminf(s[0][2], s[0][3]));
    mx1 = fmaxf(fmaxf(s[1][0], s[1][1]), fmaxf(s[1][2], s[1][3]));
    mn2 = fminf(fminf(s[2][0], s[2][1]), fminf(s[2][2], s[2][3]));
    mx2 = fmaxf(fmaxf(s[3][0], s[3][1]), fmaxf(s[3][2], s[3][3]));
    atomicMin(&keys[0], f2key(mn1));
    atomicMax(&keys[1], f2key(mx1));
    atomicMin(&keys[2], f2key(mn2));
    atomicMax(&keys[3], f2key(mx2));
  }
}

__global__ void __launch_bounds__(TPB, 4) tmqi_kernel(
    const float* __restrict__ img1, const float* __restrict__ img2,
    const unsigned int* __restrict__ keys, double* __restrict__ dsum,
    unsigned int* __restrict__ cnt, float* __restrict__ out,
    float uhdr, float inv_s) {
  __shared__ float cs[5][W + 16];  // +16 pad: last active thread reads 16 floats from col 1012
  __shared__ double wred[TPB / 64];

  const int tid = threadIdx.x;
  const int r0 = blockIdx.x * RSTRIP;
  const int b = blockIdx.y;
  const int rs = min(RSTRIP, OH - r0);
  const int c = tid * CPT;

  const float a1 = 255.0f / (key2f(keys[1]) - key2f(keys[0]) + 1e-6f);
  const float a2 = 255.0f / (key2f(keys[3]) - key2f(keys[2]) + 1e-6f);

  const float* p1 = img1 + ((size_t)b << 20) + c;
  const float* p2 = img2 + ((size_t)b << 20) + c;

  float su[4], sv[4], suu[4], svv[4], suv[4];
#pragma unroll
  for (int k = 0; k < 4; ++k) { su[k] = sv[k] = suu[k] = svv[k] = suv[k] = 0.0f; }

  // prologue: vertical sums over first 11 rows (unrolled -> batched independent loads)
#pragma unroll
  for (int j = 0; j < WSZ; ++j) {
    const int r = r0 + j;
    float4 u4 = *(const float4*)(p1 + ((size_t)r << 10));
    float4 v4 = *(const float4*)(p2 + ((size_t)r << 10));
    float uu[4] = {u4.x, u4.y, u4.z, u4.w};
    float vv[4] = {v4.x, v4.y, v4.z, v4.w};
#pragma unroll
    for (int k = 0; k < 4; ++k) {
      su[k] += uu[k]; sv[k] += vv[k];
      suu[k] = fmaf(uu[k], uu[k], suu[k]);
      svv[k] = fmaf(vv[k], vv[k], svv[k]);
      suv[k] = fmaf(uu[k], vv[k], suv[k]);
    }
  }

  double acc = 0.0;
  float4 un4, vn4, uo4, vo4;  // pipelined slide loads, integrated next iteration

#pragma unroll 1
  for (int i = 0; i < rs; ++i) {
    if (i > 0) {
      // integrate the slide loads issued last iteration (already drained at prev barrier)
      float un[4] = {un4.x, un4.y, un4.z, un4.w};
      float vn[4] = {vn4.x, vn4.y, vn4.z, vn4.w};
      float uo[4] = {uo4.x, uo4.y, uo4.z, uo4.w};
      float vo[4] = {vo4.x, vo4.y, vo4.z, vo4.w};
#pragma unroll
      for (int k = 0; k < 4; ++k) {
        su[k] += un[k] - uo[k];
        sv[k] += vn[k] - vo[k];
        suu[k] += fmaf(un[k], un[k], -uo[k] * uo[k]);
        svv[k] += fmaf(vn[k], vn[k], -vo[k] * vo[k]);
        suv[k] += fmaf(un[k], vn[k], -uo[k] * vo[k]);
      }
    }
    // publish vertical sums
    ((float4*)(cs[0]))[tid] = make_float4(su[0], su[1], su[2], su[3]);
    ((float4*)(cs[1]))[tid] = make_float4(sv[0], sv[1], sv[2], sv[3]);
    ((float4*)(cs[2]))[tid] = make_float4(suu[0], suu[1], suu[2], suu[3]);
    ((float4*)(cs[3]))[tid] = make_float4(svv[0], svv[1], svv[2], svv[3]);
    ((float4*)(cs[4]))[tid] = make_float4(suv[0], suv[1], suv[2], suv[3]);
    __syncthreads();

    // issue next slide loads NOW: their vmcnt drain at the closing barrier
    // hides under the horizontal+map compute below
    if (i + 1 < rs) {
      const int rn = r0 + i + WSZ;
      const int ro = r0 + i;
      un4 = *(const float4*)(p1 + ((size_t)rn << 10));
      vn4 = *(const float4*)(p2 + ((size_t)rn << 10));
      uo4 = *(const float4*)(p1 + ((size_t)ro << 10));
      vo4 = *(const float4*)(p2 + ((size_t)ro << 10));
    }

    if (c < OW) {
      float S[5][4];
#pragma unroll
      for (int q = 0; q < 5; ++q) {
        const float* row = cs[q];
        float4 w0 = *(const float4*)(row + c);
        float4 w1 = *(const float4*)(row + c + 4);
        float4 w2 = *(const float4*)(row + c + 8);
        float4 w3 = *(const float4*)(row + c + 12);
        float s0 = w0.x + w0.y + w0.z + w0.w + w1.x + w1.y + w1.z + w1.w +
                   w2.x + w2.y + w2.z;
        S[q][0] = s0;
        float s1 = s0 - w0.x + w2.w; S[q][1] = s1;
        float s2 = s1 - w0.y + w3.x; S[q][2] = s2;
        float s3 = s2 - w0.z + w3.y; S[q][3] = s3;
      }
#pragma unroll
      for (int k = 0; k < 4; ++k) {
        if (c + k < OW) {
          float mu_u = S[0][k] * INV121;
          float mu_v = S[1][k] * INV121;
          float varu = fmaf(-mu_u, mu_u, S[2][k] * INV121);
          float varv = fmaf(-mu_v, mu_v, S[3][k] * INV121);
          float cov  = fmaf(-mu_u, mu_v, S[4][k] * INV121);
          float s1sq = a1 * a1 * varu;
          float s2sq = a2 * a2 * varv;
          float s12  = a1 * a2 * cov;
          float sg1 = sqrtf(fmaxf(s1sq, 0.0f) + 1e-6f);
          float sg2 = sqrtf(fmaxf(s2sq, 0.0f) + 1e-6f);
          float pp1 = 0.5f * (1.0f + erff((sg1 - uhdr) * inv_s));
          float pp2 = 0.5f * (1.0f + erff((sg2 - uhdr) * inv_s));
          float smap = ((2.0f * pp1 * pp2 + 0.01f) / (pp1 * pp1 + pp2 * pp2 + 0.01f)) *
                       ((s12 + 10.0f) / (sg1 * sg2 + 10.0f));
          acc += (double)smap;
        }
      }
    }
    __syncthreads();  // vmcnt(0) drain here completes the slide loads
  }

  // block reduce (double) + last-block finalize
#pragma unroll
  for (int off = 32; off > 0; off >>= 1) acc += __shfl_down(acc, off);
  if ((tid & 63) == 0) wred[tid >> 6] = acc;
  __syncthreads();
  if (tid == 0) {
    atomicAdd(dsum, wred[0] + wred[1] + wred[2] + wred[3]);
    __threadfence();
    unsigned int n = atomicAdd(cnt, 1u);
    if (n == TGRID - 1) {
      double total = atomicAdd(dsum, 0.0);  // atomic read of final value
      out[0] = (float)(total / (double)((size_t)BATCH * OH * OW));
    }
  }
}

extern "C" void kernel_launch(void* const* d_in, const int* in_sizes, int n_in,
                              void* d_out, int out_size, void* d_ws, size_t ws_size,
                              hipStream_t stream) {
  const float* img1 = (const float*)d_in[0];
  const float* img2 = (const float*)d_in[1];
  float* out = (float*)d_out;

  unsigned int* keys = (unsigned int*)d_ws;
  double* dsum = (double*)((char*)d_ws + 16);
  unsigned int* cnt = (unsigned int*)((char*)d_ws + 24);

  const double csf = 100.0 * 2.6 * (0.0192 + 0.114 * 16.0) * exp(-pow(0.114 * 16.0, 1.1));
  const double u_hdr = 128.0 / (1.4 * csf);
  const double sig_hdr = u_hdr / 3.0;
  const float uhdr = (float)u_hdr;
  const float inv_s = (float)(1.0 / (sig_hdr * sqrt(2.0)));

  hipLaunchKernelGGL(init_ws, dim3(1), dim3(1), 0, stream, keys, dsum, cnt);
  hipLaunchKernelGGL(minmax_kernel, dim3(MM_BLOCKS), dim3(MM_TPB), 0, stream,
                     (const float4*)img1, (const float4*)img2, keys);
  dim3 grid(NSTRIP, BATCH);
  hipLaunchKernelGGL(tmqi_kernel, grid, dim3(TPB), 0, stream,
                     img1, img2, keys, dsum, cnt, out, uhdr, inv_s);
}